// Round 8
// baseline (380.689 us; speedup 1.0000x reference)
//
#include <hip/hip_runtime.h>
#include <stdint.h>

#define BZc 65536
#define DCc 512
#define NRc 1024
#define BM 64

typedef float f32x16 __attribute__((ext_vector_type(16)));
typedef float f32x4v __attribute__((ext_vector_type(4)));
typedef unsigned long long u64;

#define ZERO16 {0.f,0.f,0.f,0.f, 0.f,0.f,0.f,0.f, 0.f,0.f,0.f,0.f, 0.f,0.f,0.f,0.f}

// ---------------- prep: normalize rel_weight -> fp8 e4m3, packed as 32x32x16 MFMA
// A-operand fragments: addr(n,k8) = (n>>5)*16384 + kt*512 + hi*256 + (n&31)*8,
// where kt = k8>>1, hi = k8&1 (k8 = 8-float piece index). Also zero out[0].
__global__ void __launch_bounds__(64) ndl_prep(const float* __restrict__ rw,
                                               unsigned char* __restrict__ rwn,
                                               float* __restrict__ out) {
    if (blockIdx.x == 0 && threadIdx.x == 0) out[0] = 0.0f;
    const int t = threadIdx.x;
    const int n = blockIdx.x * 8 + (t >> 3);
    const int l8 = t & 7;                       // 8 lanes/row, 64 consecutive floats each
    const float4* src = (const float4*)(rw + (size_t)n * DCc) + l8 * 16;
    float4 v[16];
    float ss = 0.0f;
#pragma unroll
    for (int i = 0; i < 16; ++i) {
        v[i] = src[i];
        ss += v[i].x*v[i].x + v[i].y*v[i].y + v[i].z*v[i].z + v[i].w*v[i].w;
    }
    ss += __shfl_xor(ss, 1);
    ss += __shfl_xor(ss, 2);
    ss += __shfl_xor(ss, 4);
    const float inv = rsqrtf(fmaxf(ss, 1e-24f));
    unsigned char* base = rwn + ((size_t)(n >> 5) << 14) + (n & 31) * 8;
#pragma unroll
    for (int p = 0; p < 8; ++p) {               // piece p: floats k = l8*64 + p*8 .. +7
        float4 v0 = v[2*p], v1 = v[2*p+1];
        int lo = __builtin_amdgcn_cvt_pk_fp8_f32(v0.x*inv, v0.y*inv, 0,  false);
        lo     = __builtin_amdgcn_cvt_pk_fp8_f32(v0.z*inv, v0.w*inv, lo, true);
        int hi8 = __builtin_amdgcn_cvt_pk_fp8_f32(v1.x*inv, v1.y*inv, 0,  false);
        hi8     = __builtin_amdgcn_cvt_pk_fp8_f32(v1.z*inv, v1.w*inv, hi8, true);
        int2 pk; pk.x = lo; pk.y = hi8;
        const int kt = l8*4 + (p >> 1);
        const int kh = p & 1;
        *(int2*)(base + kt*512 + kh*256) = pk;
    }
}

// ---------------- main: fused fp8 A-prologue + barrier-free MFMA loop + loss ----------------
__global__ void __launch_bounds__(256, 4) ndl_main(const float* __restrict__ wo,
                                                   const unsigned char* __restrict__ rwn,
                                                   const long long* __restrict__ iy,
                                                   float* __restrict__ out) {
    __shared__ char As[BM * DCc];       // 32KB raw-fp8 wo rows, byte ^ ((r&31)<<3)
    __shared__ float invn[BM];
    __shared__ float mxw[4][BM];
    __shared__ float syw[4][BM];

    const int t = threadIdx.x;
    const int wid = t >> 6;
    const int lane = t & 63;
    const int l32 = lane & 31;
    const int hi = lane >> 5;
    const int rbase = blockIdx.x * BM;

    // y for this lane's two wo-rows, pre-adjusted for the match test
    int ymnb0 = (int)iy[rbase + l32]      - wid*32 - hi*4;
    int ymnb1 = (int)iy[rbase + 32 + l32] - wid*32 - hi*4;

    // ---- A prologue: 64 rows x 512 f32 -> raw fp8 swizzled LDS + inv-norms ----
    {
        const int r = t >> 2;
        const int q = t & 3;
        const float* src = wo + (size_t)(rbase + r) * DCc + q * 128;
        const int swz = (r & 31) << 3;
        char* rowp = As + r * DCc;
        float ss = 0.0f;
#pragma unroll
        for (int g = 0; g < 16; ++g) {
            f32x4v v0 = __builtin_nontemporal_load((const f32x4v*)(src + g*8));
            f32x4v v1 = __builtin_nontemporal_load((const f32x4v*)(src + g*8 + 4));
            ss += v0.x*v0.x + v0.y*v0.y + v0.z*v0.z + v0.w*v0.w
                + v1.x*v1.x + v1.y*v1.y + v1.z*v1.z + v1.w*v1.w;
            int lo = __builtin_amdgcn_cvt_pk_fp8_f32(v0.x, v0.y, 0,  false);
            lo     = __builtin_amdgcn_cvt_pk_fp8_f32(v0.z, v0.w, lo, true);
            int hi8 = __builtin_amdgcn_cvt_pk_fp8_f32(v1.x, v1.y, 0,  false);
            hi8     = __builtin_amdgcn_cvt_pk_fp8_f32(v1.z, v1.w, hi8, true);
            int2 pk; pk.x = lo; pk.y = hi8;
            *(int2*)(rowp + ((q*128 + g*8) ^ swz)) = pk;
        }
        ss += __shfl_xor(ss, 1);
        ss += __shfl_xor(ss, 2);
        if (q == 0) invn[r] = rsqrtf(fmaxf(ss, 1e-24f));
    }
    __syncthreads();

    const int aswz = l32 << 3;
    const char* arow0 = As + l32 * DCc;
    const char* arow1 = As + (32 + l32) * DCc;
    const char* bbase = (const char*)rwn + ((size_t)wid << 14) + lane * 8;

    f32x16 acc0 = ZERO16, acc1 = ZERO16;
    float mx0 = -1e30f, mx1 = -1e30f, sy0 = -1e30f, sy1 = -1e30f;

    auto LOADB = [&](u64* buf, int gi) {
        const char* gp = bbase + (size_t)(gi >> 2) * 65536 + (gi & 3) * 4096;
#pragma unroll
        for (int j = 0; j < 8; ++j) buf[j] = *(const u64*)(gp + j * 512);
    };
    auto CONSUME = [&](const u64* buf, int gi) {
        const int ktb = (gi & 3) * 8;
#pragma unroll
        for (int j = 0; j < 8; ++j) {
            const int ko = (ktb + j) * 16 + hi * 8;
            u64 a0 = *(const u64*)(arow0 + (ko ^ aswz));
            u64 a1 = *(const u64*)(arow1 + (ko ^ aswz));
            acc0 = __builtin_amdgcn_mfma_f32_32x32x16_fp8_fp8(buf[j], a0, acc0, 0, 0, 0);
            acc1 = __builtin_amdgcn_mfma_f32_32x32x16_fp8_fp8(buf[j], a1, acc1, 0, 0, 0);
        }
    };
    auto EPILOGUE = [&]() {
#pragma unroll
        for (int reg = 0; reg < 16; ++reg) {
            const int C = (reg & 3) + 8 * (reg >> 2);
            float s0 = acc0[reg], s1 = acc1[reg];
            const bool m0 = (C == ymnb0);
            const bool m1 = (C == ymnb1);
            sy0 = m0 ? s0 : sy0;
            sy1 = m1 ? s1 : sy1;
            mx0 = fmaxf(mx0, m0 ? -1e30f : s0);
            mx1 = fmaxf(mx1, m1 ? -1e30f : s1);
        }
        f32x16 z = ZERO16;
        acc0 = z; acc1 = z;
        ymnb0 -= 128; ymnb1 -= 128;
    };

    u64 bufA[8], bufB[8];
    LOADB(bufA, 0);
#pragma unroll 2
    for (int io = 0; io < 16; ++io) {
        const int g0 = 2 * io, g1 = 2 * io + 1;
        LOADB(bufB, g1);
        CONSUME(bufA, g0);                 // g0 even -> never an nb boundary
        if (g1 + 1 < 32) LOADB(bufA, g1 + 1);
        CONSUME(bufB, g1);
        if ((g1 & 3) == 3) EPILOGUE();     // end of nb (static after unroll 2)
    }

    // combine the two k-half lane groups (they hold different n's of same wo-row)
    mx0 = fmaxf(mx0, __shfl_xor(mx0, 32));
    mx1 = fmaxf(mx1, __shfl_xor(mx1, 32));
    sy0 = fmaxf(sy0, __shfl_xor(sy0, 32));
    sy1 = fmaxf(sy1, __shfl_xor(sy1, 32));
    if (hi == 0) {
        mxw[wid][l32]      = mx0;
        mxw[wid][32 + l32] = mx1;
        syw[wid][l32]      = sy0;
        syw[wid][32 + l32] = sy1;
    }
    __syncthreads();

    if (wid == 0) {   // one wave: 64 rows
        float ms = fmaxf(fmaxf(mxw[0][lane], mxw[1][lane]), fmaxf(mxw[2][lane], mxw[3][lane]));
        float sv = fmaxf(fmaxf(syw[0][lane], syw[1][lane]), fmaxf(syw[2][lane], syw[3][lane]));
        const float ia = invn[lane];
        ms *= ia; sv *= ia;
        const float pos = sqrtf(fmaxf(2.0f - 2.0f * sv, 0.0f));
        const float neg = sqrtf(fmaxf(2.0f - 2.0f * ms, 0.0f));
        float c = pos + fminf(fmaxf(1.0f - neg, 0.0f), 9999.0f);
#pragma unroll
        for (int d = 1; d <= 32; d <<= 1) c += __shfl_xor(c, d);
        if (lane == 0) atomicAdd(out, c * (1.0f / (float)BZc));
    }
}

extern "C" void kernel_launch(void* const* d_in, const int* in_sizes, int n_in,
                              void* d_out, int out_size, void* d_ws, size_t ws_size,
                              hipStream_t stream) {
    const float* wo = (const float*)d_in[0];
    const float* rw = (const float*)d_in[1];
    const long long* iy = (const long long*)d_in[2];
    float* out = (float*)d_out;
    unsigned char* rwn = (unsigned char*)d_ws;   // 1024*512 fp8 = 512KB packed

    ndl_prep<<<NRc / 8, 64, 0, stream>>>(rw, rwn, out);
    ndl_main<<<BZc / BM, 256, 0, stream>>>(wo, rwn, iy, out);
}